// Round 7
// baseline (143.532 us; speedup 1.0000x reference)
//
#include <hip/hip_runtime.h>
#include <hip/hip_bf16.h>

#if defined(__has_builtin)
#if __has_builtin(__builtin_amdgcn_exp2f)
#define EXP2F __builtin_amdgcn_exp2f
#endif
#if __has_builtin(__builtin_amdgcn_rcpf)
#define RCPF __builtin_amdgcn_rcpf
#endif
#endif
#ifndef EXP2F
#define EXP2F exp2f
#endif
#ifndef RCPF
#define RCPF(x) (1.0f / (x))
#endif

// Sizes (fixed by the problem)
#define B_  8
#define Q_  256
#define K_  1024
#define D_  256
#define H_  128
#define DV_ 128

#define CSL 2.8853900817779268f   // 2*log2(e)
#define L2E 1.4426950408889634f   // log2(e)

// Workspace layout (floats). ~7.4 MB used. Harness poisons the whole d_ws
// (256 MiB, ~42 us) + restores d_in (~18 us) every timed iter — fixed.
#define QE_OFF   0                // qE   [B*Q][H]                = 262144
#define KE_OFF   262144           // kET2 [B][64 p][K] float2     = 1048576
#define WPK_OFF  1310720          // wpk  [64] float4             = 256
#define AVP_OFF  1310976          // avpart [2][2048][128]        = 524288
#define SP_OFF   1835264          // spart  [2][2048]             = 4096

// ---------------------------------------------------------------------------
// proj_kernel: 320 blocks, 64 rows x 64 cols, 256 threads, 4x4 micro-tile,
// all-b128 LDS reads. Epilogue exp2(CSL*x); Q -> qE row-major; K ->
// kET2[b][p][k] float2 = (E_{2p}, E_{2p+1}).
// ---------------------------------------------------------------------------
__global__ __launch_bounds__(256) void proj_kernel(
    const float* __restrict__ queries, const float* __restrict__ keys,
    const float* __restrict__ Wq, const float* __restrict__ Wk,
    const float* __restrict__ w_v,
    float* __restrict__ qE, float2* __restrict__ kET2, float* __restrict__ wpk)
{
    __shared__ __align__(16) float As[64][68];   // [d][row], pad 68
    __shared__ __align__(16) float Ws[64][64];   // [d][col]

    const int tid = threadIdx.x;
    const int blk = blockIdx.x;
    const bool isQ = blk < 64;
    const int t = isQ ? blk : (blk - 64);
    const int rowtile = t >> 1;
    const int cbase = (t & 1) * 64;
    const int row0 = rowtile * 64;
    const float* A = isQ ? (queries + row0 * D_) : (keys + row0 * D_);
    const float* W = isQ ? Wq : Wk;

    float acc[4][4];
#pragma unroll
    for (int i = 0; i < 4; i++)
#pragma unroll
        for (int j = 0; j < 4; j++) acc[i][j] = 0.f;

    const int lr  = tid & 63;          // A-stage row
    const int ldb = (tid >> 6) * 16;   // A-stage d base
    const int r4  = (tid >> 4) * 4;    // compute row base 0..60
    const int c4  = (tid & 15) * 4;    // compute col base 0..60

    for (int d0 = 0; d0 < D_; d0 += 64) {
#pragma unroll
        for (int j = 0; j < 4; j++) {
            const float4 a = *(const float4*)&A[lr * D_ + d0 + ldb + j * 4];
            As[ldb + j * 4 + 0][lr] = a.x;
            As[ldb + j * 4 + 1][lr] = a.y;
            As[ldb + j * 4 + 2][lr] = a.z;
            As[ldb + j * 4 + 3][lr] = a.w;
        }
#pragma unroll
        for (int l = 0; l < 4; l++) {
            const int idx = tid + l * 256;
            const int rr = idx >> 4, cc = (idx & 15) * 4;
            *(float4*)&Ws[rr][cc] = *(const float4*)&W[(d0 + rr) * H_ + cbase + cc];
        }
        __syncthreads();
#pragma unroll 4
        for (int d = 0; d < 64; d++) {
            const float4 a4 = *(const float4*)&As[d][r4];
            const float4 w4 = *(const float4*)&Ws[d][c4];
            const float ar[4] = {a4.x, a4.y, a4.z, a4.w};
#pragma unroll
            for (int i = 0; i < 4; i++) {
                acc[i][0] = fmaf(ar[i], w4.x, acc[i][0]);
                acc[i][1] = fmaf(ar[i], w4.y, acc[i][1]);
                acc[i][2] = fmaf(ar[i], w4.z, acc[i][2]);
                acc[i][3] = fmaf(ar[i], w4.w, acc[i][3]);
            }
        }
        __syncthreads();
    }

#pragma unroll
    for (int i = 0; i < 4; i++) {
        float e[4];
#pragma unroll
        for (int j = 0; j < 4; j++) e[j] = EXP2F(CSL * acc[i][j]);
        const int row = row0 + r4 + i;
        if (isQ) {
            *(float4*)&qE[row * H_ + cbase + c4] = make_float4(e[0], e[1], e[2], e[3]);
        } else {
            const int b = row >> 10, k = row & 1023;
            const int p0 = (cbase + c4) >> 1;
            kET2[(size_t)(b * 64 + p0) * K_ + k]     = make_float2(e[0], e[1]);
            kET2[(size_t)(b * 64 + p0 + 1) * K_ + k] = make_float2(e[2], e[3]);
        }
    }

    if (blk == 0 && tid < 64) {
        const float w1 = -2.0f * L2E * w_v[2 * tid];
        const float w2 = -2.0f * L2E * w_v[2 * tid + 1];
        *(float4*)&wpk[tid * 4] = make_float4(w1, w2, w1 + w2, 0.f);
    }
}

// ---------------------------------------------------------------------------
// attn_kernel: 512 blocks x 512 threads. Block = (kh 0/1, b, qt):
//   kh = raw>>8, j = raw&255, b = (j+kh)&7  (scramble so a CU's co-resident
//   pair comes from different batches), qt = j>>3. Block: 8 q-rows x 512 k.
// Thread: 1 k, 8 q accumulators. kET2 traffic amortized over 8 q-rows
// (round-6 regression: G=2 doubled traffic -> L3-bound at 11.6 TB/s).
// Writes PARTIAL row-sums and PARTIAL AV to ws; combine_kernel finishes.
// h-pairing: w1/(1+x1)+w2/(1+x2) = [(w1+w2)+w1*x2+w2*x1]/[(1+x1)(1+x2)].
// ---------------------------------------------------------------------------
__global__ __launch_bounds__(512, 4) void attn_kernel(
    const float* __restrict__ qE,       // [B*Q][H] = e^{2q}
    const float2* __restrict__ kET2,    // [B][64][K] h-pairs of e^{2k}
    const float* __restrict__ values,   // [B][K][DV]
    const int*   __restrict__ valid_lens,
    const float* __restrict__ wpk,      // [64] float4 (w1,w2,w1+w2,0)
    float* __restrict__ avpart,         // [2][2048][128]
    float* __restrict__ spart)          // [2][2048]
{
    __shared__ __align__(16) float sc[512][8];      // 16 KB p-values
    __shared__ __align__(16) float red[4][8][128];  // 16 KB AV k-split partials
    __shared__ __align__(16) float psum[8][8];      // [wave][q]

    const int tid = threadIdx.x;
    const int raw = blockIdx.x;
    const int kh  = raw >> 8;            // k-half 0/1
    const int j   = raw & 255;
    const int b   = (j + kh) & 7;
    const int qt  = j >> 3;              // 0..31
    const int q0  = qt * 8;
    const int vl  = valid_lens[b];
    const int k   = kh * 512 + tid;

    const float* qp = qE + (b * Q_ + q0) * H_;   // 8 consecutive rows

    float acc[8];
#pragma unroll
    for (int q = 0; q < 8; q++) acc[q] = 0.f;

    if (k < vl) {
        const float2* kb = kET2 + (size_t)(b * 64) * K_ + k;
#pragma unroll 2
        for (int p = 0; p < 64; p++) {
            const float2 ek = kb[(size_t)p * K_];
            const float4 wp = *(const float4*)&wpk[p * 4];
#pragma unroll
            for (int q = 0; q < 8; q++) {
                const float2 qq = *(const float2*)&qp[q * H_ + 2 * p];
                const float x1 = qq.x * ek.x, x2 = qq.y * ek.y;
                const float e1 = x1 + 1.f;
                const float d  = fmaf(e1, x2, e1);
                float n = fmaf(wp.y, x1, wp.z);
                n = fmaf(wp.x, x2, n);
                acc[q] = fmaf(n, RCPF(d), acc[q]);
            }
        }
    }

    // ---- exp + mask; write sc row; wave-reduce partial row sums ----
    const bool valid = k < vl;
    float p8[8];
#pragma unroll
    for (int q = 0; q < 8; q++) p8[q] = valid ? EXP2F(acc[q]) : 0.f;
    *(float4*)&sc[tid][0] = make_float4(p8[0], p8[1], p8[2], p8[3]);
    *(float4*)&sc[tid][4] = make_float4(p8[4], p8[5], p8[6], p8[7]);

    float s8[8];
#pragma unroll
    for (int q = 0; q < 8; q++) s8[q] = p8[q];
#pragma unroll
    for (int sh = 32; sh > 0; sh >>= 1) {
#pragma unroll
        for (int q = 0; q < 8; q++) s8[q] += __shfl_xor(s8[q], sh);
    }
    const int lane = tid & 63, w = tid >> 6;
    if (lane == 0) {
        *(float4*)&psum[w][0] = make_float4(s8[0], s8[1], s8[2], s8[3]);
        *(float4*)&psum[w][4] = make_float4(s8[4], s8[5], s8[6], s8[7]);
    }
    __syncthreads();
    if (tid < 8) {
        float t = 0.f;
#pragma unroll
        for (int ww = 0; ww < 8; ww++) t += psum[ww][tid];
        spart[kh * 2048 + b * Q_ + q0 + tid] = t;
    }

    // ---- partial AV: thread = (ks 0..3, qp2 0..3, v4 0..31) ----
    const int v4  = tid & 31;
    const int qp2 = (tid >> 5) & 3;      // q-pair
    const int ks  = tid >> 7;            // k sub-split
    const float* vb = values + (size_t)b * (K_ * DV_) + v4 * 4;
    float av[2][4];
#pragma unroll
    for (int qq = 0; qq < 2; qq++)
#pragma unroll
        for (int jj = 0; jj < 4; jj++) av[qq][jj] = 0.f;

    const int kbase = kh * 512 + ks * 128;
    const int rem = vl - kbase;
    const int imax = rem <= 0 ? 0 : (rem > 128 ? 128 : rem);
#pragma unroll 2
    for (int i = 0; i < imax; i++) {
        const int kl = ks * 128 + i;                       // local sc row
        const float4 vv = *(const float4*)&vb[(kbase + i) * DV_];
        const float2 pp = *(const float2*)&sc[kl][2 * qp2]; // LDS broadcast
        av[0][0] = fmaf(pp.x, vv.x, av[0][0]); av[0][1] = fmaf(pp.x, vv.y, av[0][1]);
        av[0][2] = fmaf(pp.x, vv.z, av[0][2]); av[0][3] = fmaf(pp.x, vv.w, av[0][3]);
        av[1][0] = fmaf(pp.y, vv.x, av[1][0]); av[1][1] = fmaf(pp.y, vv.y, av[1][1]);
        av[1][2] = fmaf(pp.y, vv.z, av[1][2]); av[1][3] = fmaf(pp.y, vv.w, av[1][3]);
    }
    *(float4*)&red[ks][2 * qp2][v4 * 4]     = make_float4(av[0][0], av[0][1], av[0][2], av[0][3]);
    *(float4*)&red[ks][2 * qp2 + 1][v4 * 4] = make_float4(av[1][0], av[1][1], av[1][2], av[1][3]);
    __syncthreads();

    if (tid < 256) {
        const int q = tid >> 5, vv4 = tid & 31;
        float4 t = make_float4(0.f, 0.f, 0.f, 0.f);
#pragma unroll
        for (int g = 0; g < 4; g++) {
            const float4 r = *(const float4*)&red[g][q][vv4 * 4];
            t.x += r.x; t.y += r.y; t.z += r.z; t.w += r.w;
        }
        *(float4*)&avpart[(size_t)(kh * 2048 + b * Q_ + q0 + q) * DV_ + vv4 * 4] = t;
    }
}

// ---------------------------------------------------------------------------
// combine_kernel: out[row][v] = (av0+av1) * rcp(s0+s1). 256 blocks x 256 thr,
// 4 elems/thread (one float4; all 4 share the same row since DV=128).
// ---------------------------------------------------------------------------
__global__ __launch_bounds__(256) void combine_kernel(
    const float* __restrict__ avpart, const float* __restrict__ spart,
    float* __restrict__ out)
{
    const int idx = (blockIdx.x * 256 + threadIdx.x) * 4;   // 0..262140
    const int row = idx >> 7;
    const float4 a0 = *(const float4*)&avpart[idx];
    const float4 a1 = *(const float4*)&avpart[2048 * DV_ + idx];
    const float r = RCPF(spart[row] + spart[2048 + row]);
    *(float4*)&out[idx] = make_float4((a0.x + a1.x) * r, (a0.y + a1.y) * r,
                                      (a0.z + a1.z) * r, (a0.w + a1.w) * r);
}

extern "C" void kernel_launch(void* const* d_in, const int* in_sizes, int n_in,
                              void* d_out, int out_size, void* d_ws, size_t ws_size,
                              hipStream_t stream) {
    const float* queries    = (const float*)d_in[0];  // [8,256,256]
    const float* keys       = (const float*)d_in[1];  // [8,1024,256]
    const float* values     = (const float*)d_in[2];  // [8,1024,128]
    const int*   valid_lens = (const int*)d_in[3];    // [8]
    const float* W_q        = (const float*)d_in[4];  // [256,128]
    const float* W_k        = (const float*)d_in[5];  // [256,128]
    const float* w_v        = (const float*)d_in[6];  // [128]
    float* out = (float*)d_out;

    float*  ws     = (float*)d_ws;
    float*  qE     = ws + QE_OFF;
    float2* kET2   = (float2*)(ws + KE_OFF);
    float*  wpk    = ws + WPK_OFF;
    float*  avpart = ws + AVP_OFF;
    float*  spart  = ws + SP_OFF;

    proj_kernel<<<320, 256, 0, stream>>>(queries, keys, W_q, W_k, w_v, qE, kET2, wpk);
    attn_kernel<<<512, 512, 0, stream>>>(qE, kET2, values, valid_lens, wpk, avpart, spart);
    combine_kernel<<<256, 256, 0, stream>>>(avpart, spart, out);
}